// Round 4
// baseline (738.001 us; speedup 1.0000x reference)
//
#include <hip/hip_runtime.h>
#include <math.h>

#define NN   1536
#define DG   32
#define BB   8
#define OBSD 33
#define HID  64
#define NHEAD 4
#define EE   (NN*DG)   // 49152

__device__ __forceinline__ float sigm(float x){ return 1.0f/(1.0f+expf(-x)); }

// ---------------- K0: ObsEmbedding + GRU input transform, all (B,N) ----------------
// Also zeros the CSR cursor array (blocks 0..5), removing a memset dispatch.
__global__ void __launch_bounds__(256) k_embgi(
                      const float* __restrict__ Ht,
                      const float* __restrict__ We1, const float* __restrict__ be1,
                      const float* __restrict__ We2, const float* __restrict__ be2,
                      const float* __restrict__ lng, const float* __restrict__ lnb,
                      const float* __restrict__ Wih, const float* __restrict__ bih,
                      float* __restrict__ GI, int* __restrict__ cursor){
    __shared__ float lwih[192*33];
    int tid = threadIdx.x;
    if(blockIdx.x < 6) cursor[blockIdx.x*256 + tid] = 0;
    for(int i=tid;i<192*32;i+=256){ int r=i>>5, c=i&31; lwih[r*33+c]=Wih[i]; }
    __syncthreads();
    int lane = tid & 63;
    int j32 = lane & 31;
    int bn = blockIdx.x*4 + (tid>>6);       // 0 .. B*N-1  (t-major)
    const float* hrow = Ht + (size_t)bn*OBSD;
    float x1 = be1[j32];
    for(int o=0;o<OBSD;o++) x1 += hrow[o]*We1[o*32+j32];
    x1 = fmaxf(x1,0.f);
    float x2 = be2[j32];
    for(int i=0;i<32;i++){
        float xi = __shfl(x1, (lane & 32) | i, 64);
        x2 += xi * We2[i*32+j32];
    }
    x2 = fmaxf(x2,0.f);
    float mu = x2;
    for(int m=16;m>=1;m>>=1) mu += __shfl_xor(mu, m, 32);
    mu *= (1.0f/32.0f);
    float d = x2-mu; float var = d*d;
    for(int m=16;m>=1;m>>=1) var += __shfl_xor(var, m, 32);
    var *= (1.0f/32.0f);
    float xln = d*rsqrtf(var+1e-5f)*lng[j32]+lnb[j32];
    int j = lane;
    float gr=bih[j], gz=bih[64+j], gn=bih[128+j];
    for(int kk=0;kk<32;kk++){
        float ek = __shfl(xln, kk, 64);
        gr += ek*lwih[j*33+kk];
        gz += ek*lwih[(64+j)*33+kk];
        gn += ek*lwih[(128+j)*33+kk];
    }
    float* g = GI + (size_t)bn*192;
    g[j]=gr; g[64+j]=gz; g[128+j]=gn;
}

// ---------------- CSR build (dst constant across steps) ----------------
__global__ void k_count(const int* __restrict__ dst, int* __restrict__ cursor){
    int e = blockIdx.x*256+threadIdx.x;
    if(e<EE) atomicAdd(&cursor[dst[e]],1);
}
__global__ void k_scan(int* __restrict__ cnt, int* __restrict__ indptr){
    __shared__ int part[256];
    int t = threadIdx.x;
    int local[6]; int s=0;
    for(int i=0;i<6;i++){ local[i]=cnt[t*6+i]; s+=local[i]; }
    part[t]=s; __syncthreads();
    if(t==0){ int acc=0; for(int i=0;i<256;i++){ int v=part[i]; part[i]=acc; acc+=v; } }
    __syncthreads();
    int pre = part[t];
    for(int i=0;i<6;i++){ int idx=t*6+i; indptr[idx]=pre; cnt[idx]=pre; pre+=local[i]; }
    if(t==255) indptr[NN]=EE;
}
__global__ void k_fill(const int* __restrict__ dst, int* __restrict__ cursor, int* __restrict__ eids){
    int e = blockIdx.x*256+threadIdx.x;
    if(e<EE){ int p = atomicAdd(&cursor[dst[e]],1); eids[p]=e; }
}

// ---------------- K1: 8 GRU steps + per-step P,Q,xh,a_s,a_d (fused epilogue) ----------------
// h_new is in registers when the epilogue runs -> Hall buffer eliminated.
// All weights LDS-staged (91 KB -> 1 block/CU, 256 blocks = 256 CUs, 6 nodes/block).
// Whh pad-65 and stride-64/32 reads are 2-way-per-bank = conflict-free.
// Inner loops unrolled: __shfl(hold,kk) with constant kk lowers to v_readlane (no LDS).
__global__ void __launch_bounds__(384) k_grupost(const float* __restrict__ GI,
                       const float* __restrict__ Whh, const float* __restrict__ bhh,
                       const float* __restrict__ Ws1, const float* __restrict__ Wgat,
                       const float* __restrict__ atts, const float* __restrict__ attd,
                       float* __restrict__ P, float* __restrict__ Q,
                       float* __restrict__ xh, float* __restrict__ as_, float* __restrict__ ad_){
    __shared__ float lw[192*65];      // 49920 B
    __shared__ float ws1l[128*64];    // 32768 B
    __shared__ float wgl[64*32];      //  8192 B
    int tid = threadIdx.x;
    for(int i=tid;i<192*64;i+=384){ int r=i>>6, c=i&63; lw[r*65+c]=Whh[i]; }
    for(int i=tid;i<128*64;i+=384) ws1l[i]=Ws1[i];
    for(int i=tid;i<64*32;i+=384)  wgl[i]=Wgat[i];
    __syncthreads();
    int node = blockIdx.x*6 + (tid>>6);
    int j = tid&63;
    float b_r=bhh[j], b_z=bhh[64+j], b_n=bhh[128+j];
    const float* lwr = lw + j*65;
    const float* lwz = lw + (64+j)*65;
    const float* lwn = lw + (128+j)*65;
    float atsv = (j<32)?atts[j]:0.f;
    float atdv = (j<32)?attd[j]:0.f;
    float hold = 0.f;                       // h0 = zeros
    for(int t=0;t<BB;t++){
        float hr=b_r, hz=b_z, hn=b_n;
        #pragma unroll
        for(int kk=0;kk<64;kk++){
            float hk = __shfl(hold,kk);
            hr += hk*lwr[kk];
            hz += hk*lwz[kk];
            hn += hk*lwn[kk];
        }
        const float* g = GI + ((size_t)t*NN+node)*192;
        float r  = sigm(g[j]     + hr);
        float z  = sigm(g[64+j]  + hz);
        float nn_= tanhf(g[128+j] + r*hn);
        hold = (1.f-z)*nn_ + z*hold;
        // ---- fused epilogue: P,Q (scorer halves), xh, a_s, a_d ----
        float p=0.f, q=0.f, xv=0.f;
        #pragma unroll
        for(int kk=0;kk<64;kk++){
            float hk = __shfl(hold,kk);
            p += hk*ws1l[kk*64+j];
            q += hk*ws1l[(64+kk)*64+j];
            if(j<32) xv += hk*wgl[kk*32+j];
        }
        size_t bn = (size_t)t*NN+node;
        P[bn*64+j]=p; Q[bn*64+j]=q;
        if(j<32){
            xh[bn*32+j]=xv;
            float asv = xv*atsv;
            float adv = xv*atdv;
            for(int m=1;m<8;m<<=1){ asv += __shfl_xor(asv,m); adv += __shfl_xor(adv,m); }
            if((j&7)==0){ as_[bn*4+(j>>3)]=asv; ad_[bn*4+(j>>3)]=adv; }
        }
    }
}

// ---------------- K2: edge scores + per-source-row top-k, all t ----------------
// Per-lane edge (R2 form, proven faster than reduce form): lane owns one edge,
// 16 independent float4 loads over the j-dim; Q is L2-resident (3 MB/step).
__global__ void __launch_bounds__(256) k_edge(const float* __restrict__ P, const float* __restrict__ Q,
                       const float* __restrict__ bs1, const float* __restrict__ Ws2,
                       const float* __restrict__ bs2, const int* __restrict__ dst,
                       const int* __restrict__ kptr, float* __restrict__ wbuf){
    int tid = threadIdx.x;
    int t = blockIdx.y;
    int row = blockIdx.x*8 + (tid>>5);
    int d = tid & 31;
    int e = row*DG + d;
    int de = dst[e];
    const float4* Pr = (const float4*)(P + ((size_t)t*NN+row)*64);
    const float4* Qr = (const float4*)(Q + ((size_t)t*NN+de)*64);
    const float4* B1 = (const float4*)bs1;
    const float4* W2 = (const float4*)Ws2;
    float acc = 0.f;
    #pragma unroll
    for(int jj=0;jj<16;jj++){
        float4 pv=Pr[jj], qv=Qr[jj], bv=B1[jj], wv=W2[jj];
        acc += fmaxf(pv.x+qv.x+bv.x,0.f)*wv.x;
        acc += fmaxf(pv.y+qv.y+bv.y,0.f)*wv.y;
        acc += fmaxf(pv.z+qv.z+bv.z,0.f)*wv.z;
        acc += fmaxf(pv.w+qv.w+bv.w,0.f)*wv.w;
    }
    float score = sigm(acc + bs2[0]);
    int kk = kptr[0]; if(kk>32) kk=32; if(kk<0) kk=0;
    bool sel=false;
    for(int it=0; it<kk; it++){
        float v = sel ? -INFINITY : score;
        int idx = d;
        for(int m=16;m>=1;m>>=1){
            float ov = __shfl_xor(v,m,32);
            int   oi = __shfl_xor(idx,m,32);
            if(ov>v || (ov==v && oi<idx)){ v=ov; idx=oi; }  // lax.top_k tie-break: lowest index
        }
        if(idx==d) sel=true;
    }
    wbuf[(size_t)t*EE + e] = sel ? score : 0.f;
}

// ---------------- K3: per-dst masked softmax + message aggregation, all t ----------------
__global__ void __launch_bounds__(256) k_soft(const int* __restrict__ indptr, const int* __restrict__ eids,
                       const float* __restrict__ as_, const float* __restrict__ ad_,
                       const float* __restrict__ wbuf, const float* __restrict__ xhb,
                       const float* __restrict__ bgat,
                       float* __restrict__ alphab, float* __restrict__ outp){
    int n = blockIdx.x;
    int t = blockIdx.y;
    int h = threadIdx.x>>6;
    int lane = threadIdx.x&63;
    const float* w     = wbuf  + (size_t)t*EE;
    const float* asb   = as_   + (size_t)t*NN*4;
    const float* xhbt  = xhb   + (size_t)t*NN*32;
    float*       alpha = alphab+ (size_t)t*EE*4;
    int beg = indptr[n], end = indptr[n+1];
    int deg = end-beg;
    float adv = ad_[((size_t)t*NN+n)*4+h];
    float acc[8];
    #pragma unroll
    for(int c=0;c<8;c++) acc[c]=0.f;
    if(deg<=64){
        bool valid = lane<deg;
        int e = valid ? eids[beg+lane] : 0;
        float we = valid ? w[e] : 0.f;
        bool kept = we>0.f;
        int s = e>>5;
        float lg = -INFINITY, ex = 0.f;
        if(kept){
            lg = asb[s*4+h]+adv;
            lg = lg>0.f ? lg : 0.2f*lg;
        }
        float m = lg;
        for(int mm=32;mm>=1;mm>>=1) m = fmaxf(m,__shfl_xor(m,mm));
        if(kept) ex = expf(lg-m);
        float ssum = ex;
        for(int mm=32;mm>=1;mm>>=1) ssum += __shfl_xor(ssum,mm);
        float inv = 1.0f/fmaxf(ssum,1e-16f);
        if(kept){
            float a = ex*inv;
            alpha[e*4+h] = a;
            float aw = a*we;
            const float4* xr = (const float4*)(xhbt + s*32 + h*8);
            float4 x0 = xr[0], x1 = xr[1];
            acc[0]+=aw*x0.x; acc[1]+=aw*x0.y; acc[2]+=aw*x0.z; acc[3]+=aw*x0.w;
            acc[4]+=aw*x1.x; acc[5]+=aw*x1.y; acc[6]+=aw*x1.z; acc[7]+=aw*x1.w;
        }
    } else {
        float m = -INFINITY;
        for(int i=beg+lane;i<end;i+=64){
            int e = eids[i];
            if(w[e]>0.f){
                float lg = asb[(e>>5)*4+h]+adv;
                lg = lg>0.f ? lg : 0.2f*lg;
                m = fmaxf(m,lg);
            }
        }
        for(int mm=32;mm>=1;mm>>=1) m = fmaxf(m,__shfl_xor(m,mm));
        float ssum=0.f;
        for(int i=beg+lane;i<end;i+=64){
            int e = eids[i];
            float ex = 0.f;
            if(w[e]>0.f){
                float lg = asb[(e>>5)*4+h]+adv;
                lg = lg>0.f ? lg : 0.2f*lg;
                ex = expf(lg-m);
            }
            alpha[e*4+h]=ex;
            ssum += ex;
        }
        for(int mm=32;mm>=1;mm>>=1) ssum += __shfl_xor(ssum,mm);
        float inv = 1.0f/fmaxf(ssum,1e-16f);
        for(int i=beg+lane;i<end;i+=64){
            int e = eids[i];
            if(w[e]>0.f){
                float a = alpha[e*4+h]*inv;
                alpha[e*4+h]=a;
                float aw = a*w[e];
                const float* xr = xhbt + (e>>5)*32 + h*8;
                #pragma unroll
                for(int c=0;c<8;c++) acc[c] += aw*xr[c];
            }
        }
    }
    for(int mm=32;mm>=1;mm>>=1){
        #pragma unroll
        for(int c=0;c<8;c++) acc[c] += __shfl_xor(acc[c],mm);
    }
    if(lane==0){
        float* o = outp + ((size_t)t*NN+n)*32 + h*8;
        float4 o0 = { acc[0]+bgat[h*8+0], acc[1]+bgat[h*8+1], acc[2]+bgat[h*8+2], acc[3]+bgat[h*8+3] };
        float4 o1 = { acc[4]+bgat[h*8+4], acc[5]+bgat[h*8+5], acc[6]+bgat[h*8+6], acc[7]+bgat[h*8+7] };
        ((float4*)o)[0]=o0; ((float4*)o)[1]=o1;
    }
}

// ---------------- K4: sparse-aware dense A row write, all t ----------------
// <=k nonzeros per row compacted into LDS; stream float4 zeros with patched entries.
__global__ void __launch_bounds__(256) k_scatter(const float* __restrict__ alphab,
                       const float* __restrict__ wbuf,
                       const int* __restrict__ dst, float* __restrict__ attn){
    __shared__ int   kde[DG];
    __shared__ float kan[DG][NHEAD];
    __shared__ int   scnt;
    int n = blockIdx.x;
    int t = blockIdx.y;
    int tid = threadIdx.x;
    const float* alpha = alphab + (size_t)t*EE*4;
    const float* w     = wbuf   + (size_t)t*EE;
    if(tid<64){
        int d = tid;
        int e = n*DG + d;
        bool kept = false;
        if(d<DG) kept = (w[e] > 0.f);
        unsigned long long mask = __ballot(kept);
        float4 av = {0.f,0.f,0.f,0.f};
        int de = 0;
        if(kept){ de = dst[e]; av = *(const float4*)(alpha + (size_t)e*4); }
        float s0=av.x, s1=av.y, s2=av.z, s3=av.w;
        for(int m=32;m>=1;m>>=1){
            s0 += __shfl_xor(s0,m); s1 += __shfl_xor(s1,m);
            s2 += __shfl_xor(s2,m); s3 += __shfl_xor(s3,m);
        }
        if(kept){
            int pos = __popcll(mask & ((1ull<<d)-1ull));
            kde[pos] = de;
            kan[pos][0] = av.x / fmaxf(s0,1e-9f);
            kan[pos][1] = av.y / fmaxf(s1,1e-9f);
            kan[pos][2] = av.z / fmaxf(s2,1e-9f);
            kan[pos][3] = av.w / fmaxf(s3,1e-9f);
        }
        if(tid==0) scnt = __popcll(mask);
    }
    __syncthreads();
    int cnt = scnt;
    size_t base = (size_t)t*NHEAD*NN*NN + (size_t)n*NN;
    #pragma unroll
    for(int it=0; it<6; it++){
        int c = it*256 + tid;          // 0..1535 over (head, 16B-chunk)
        int h = c/(NN/4), c4 = c%(NN/4);
        float4 f4 = {0.f,0.f,0.f,0.f};
        for(int p=0;p<cnt;p++){
            int de = kde[p];
            if((de>>2)==c4) ((float*)&f4)[de&3] += kan[p][h];
        }
        ((float4*)(attn + base + (size_t)h*NN*NN))[c4] = f4;
    }
}

extern "C" void kernel_launch(void* const* d_in, const int* in_sizes, int n_in,
                              void* d_out, int out_size, void* d_ws, size_t ws_size,
                              hipStream_t stream) {
    const float* Ht   = (const float*)d_in[0];
    const int*   dst  = (const int*)  d_in[2];
    const int*   kptr = (const int*)  d_in[3];
    const float* We1  = (const float*)d_in[4];
    const float* be1  = (const float*)d_in[5];
    const float* We2  = (const float*)d_in[6];
    const float* be2  = (const float*)d_in[7];
    const float* lng  = (const float*)d_in[8];
    const float* lnb  = (const float*)d_in[9];
    const float* Wih  = (const float*)d_in[10];
    const float* Whh  = (const float*)d_in[11];
    const float* bih  = (const float*)d_in[12];
    const float* bhh  = (const float*)d_in[13];
    const float* Ws1  = (const float*)d_in[14];
    const float* bs1  = (const float*)d_in[15];
    const float* Ws2  = (const float*)d_in[16];
    const float* bs2  = (const float*)d_in[17];
    const float* Wgat = (const float*)d_in[18];
    const float* atts = (const float*)d_in[19];
    const float* attd = (const float*)d_in[20];
    const float* bgat = (const float*)d_in[21];

    float* outp = (float*)d_out;                       // (B,N,32)
    float* attn = outp + (size_t)BB*NN*32;             // (B,HEADS,N,N)

    float* ws    = (float*)d_ws;
    float* GI    = ws;                    // 2359296
    float* P     = ws + 2359296;          //  786432
    float* Q     = ws + 3145728;          //  786432
    float* xh    = ws + 3932160;          //  393216
    float* as_   = ws + 4325376;          //   49152
    float* ad_   = ws + 4374528;          //   49152
    float* wbuf  = ws + 4423680;          //  393216
    float* alpha = ws + 4816896;          // 1572864
    int*   ibase = (int*)(ws + 6389760);
    int*   cursor= ibase;                 // NN
    int*   indptr= ibase + 2048;          // NN+1
    int*   eids  = ibase + 4096;          // EE

    k_embgi<<<BB*NN/4, 256, 0, stream>>>(Ht, We1, be1, We2, be2, lng, lnb, Wih, bih, GI, cursor);
    k_count<<<EE/256, 256, 0, stream>>>(dst, cursor);
    k_scan<<<1, 256, 0, stream>>>(cursor, indptr);
    k_fill<<<EE/256, 256, 0, stream>>>(dst, cursor, eids);
    k_grupost<<<NN/6, 384, 0, stream>>>(GI, Whh, bhh, Ws1, Wgat, atts, attd, P, Q, xh, as_, ad_);
    {
        dim3 ge(NN/8, BB);
        k_edge<<<ge, 256, 0, stream>>>(P, Q, bs1, Ws2, bs2, dst, kptr, wbuf);
        dim3 g(NN, BB);
        k_soft<<<g, 256, 0, stream>>>(indptr, eids, as_, ad_, wbuf, xh, bgat, alpha, outp);
        k_scatter<<<g, 256, 0, stream>>>(alpha, wbuf, dst, attn);
    }
}

// Round 5
// 536.385 us; speedup vs baseline: 1.3759x; 1.3759x over previous
//
#include <hip/hip_runtime.h>
#include <math.h>

#define NN   1536
#define DG   32
#define BB   8
#define OBSD 33
#define HID  64
#define NHEAD 4
#define EE   (NN*DG)   // 49152

__device__ __forceinline__ float sigm(float x){ return 1.0f/(1.0f+expf(-x)); }

// ---------------- K0: ObsEmbedding + GRU input transform, all (B,N) ----------------
// Also zeros the CSR cursor array (blocks 0..5), removing a memset dispatch.
__global__ void __launch_bounds__(256) k_embgi(
                      const float* __restrict__ Ht,
                      const float* __restrict__ We1, const float* __restrict__ be1,
                      const float* __restrict__ We2, const float* __restrict__ be2,
                      const float* __restrict__ lng, const float* __restrict__ lnb,
                      const float* __restrict__ Wih, const float* __restrict__ bih,
                      float* __restrict__ GI, int* __restrict__ cursor){
    __shared__ float lwih[192*33];
    int tid = threadIdx.x;
    if(blockIdx.x < 6) cursor[blockIdx.x*256 + tid] = 0;
    for(int i=tid;i<192*32;i+=256){ int r=i>>5, c=i&31; lwih[r*33+c]=Wih[i]; }
    __syncthreads();
    int lane = tid & 63;
    int j32 = lane & 31;
    int bn = blockIdx.x*4 + (tid>>6);       // 0 .. B*N-1  (t-major)
    const float* hrow = Ht + (size_t)bn*OBSD;
    float x1 = be1[j32];
    for(int o=0;o<OBSD;o++) x1 += hrow[o]*We1[o*32+j32];
    x1 = fmaxf(x1,0.f);
    float x2 = be2[j32];
    for(int i=0;i<32;i++){
        float xi = __shfl(x1, (lane & 32) | i, 64);
        x2 += xi * We2[i*32+j32];
    }
    x2 = fmaxf(x2,0.f);
    float mu = x2;
    for(int m=16;m>=1;m>>=1) mu += __shfl_xor(mu, m, 32);
    mu *= (1.0f/32.0f);
    float d = x2-mu; float var = d*d;
    for(int m=16;m>=1;m>>=1) var += __shfl_xor(var, m, 32);
    var *= (1.0f/32.0f);
    float xln = d*rsqrtf(var+1e-5f)*lng[j32]+lnb[j32];
    int j = lane;
    float gr=bih[j], gz=bih[64+j], gn=bih[128+j];
    for(int kk=0;kk<32;kk++){
        float ek = __shfl(xln, kk, 64);
        gr += ek*lwih[j*33+kk];
        gz += ek*lwih[(64+j)*33+kk];
        gn += ek*lwih[(128+j)*33+kk];
    }
    float* g = GI + (size_t)bn*192;
    g[j]=gr; g[64+j]=gz; g[128+j]=gn;
}

// ---------------- CSR build (dst constant across steps) ----------------
__global__ void k_count(const int* __restrict__ dst, int* __restrict__ cursor){
    int e = blockIdx.x*256+threadIdx.x;
    if(e<EE) atomicAdd(&cursor[dst[e]],1);
}
__global__ void k_scan(int* __restrict__ cnt, int* __restrict__ indptr){
    __shared__ int part[256];
    int t = threadIdx.x;
    int local[6]; int s=0;
    for(int i=0;i<6;i++){ local[i]=cnt[t*6+i]; s+=local[i]; }
    part[t]=s; __syncthreads();
    if(t==0){ int acc=0; for(int i=0;i<256;i++){ int v=part[i]; part[i]=acc; acc+=v; } }
    __syncthreads();
    int pre = part[t];
    for(int i=0;i<6;i++){ int idx=t*6+i; indptr[idx]=pre; cnt[idx]=pre; pre+=local[i]; }
    if(t==255) indptr[NN]=EE;
}
__global__ void k_fill(const int* __restrict__ dst, int* __restrict__ cursor, int* __restrict__ eids){
    int e = blockIdx.x*256+threadIdx.x;
    if(e<EE){ int p = atomicAdd(&cursor[dst[e]],1); eids[p]=e; }
}

// ---------------- K1: ALL 8 GRU steps in one dispatch (R2 proven form) ----------------
// LDS weight reads (pad-65: 2-way/bank = free). NO register weight cache, NO forced
// unroll — R3/R4 showed those spill at the 128-VGPR cap (FETCH_SIZE 236 MB = reloads).
__global__ void __launch_bounds__(384) k_gru_all(const float* __restrict__ GI,
                       const float* __restrict__ Whh, const float* __restrict__ bhh,
                       float* __restrict__ Hall){
    __shared__ float lw[192*65];
    int tid = threadIdx.x;
    for(int i=tid;i<192*64;i+=384){ int r=i>>6, c=i&63; lw[r*65+c]=Whh[i]; }
    __syncthreads();
    int node = blockIdx.x*6 + (tid>>6);
    int j = tid&63;
    float b_r=bhh[j], b_z=bhh[64+j], b_n=bhh[128+j];
    const float* lwr = lw + j*65;
    const float* lwz = lw + (64+j)*65;
    const float* lwn = lw + (128+j)*65;
    float hold = 0.f;                       // h0 = zeros
    for(int t=0;t<BB;t++){
        float hr=b_r, hz=b_z, hn=b_n;
        for(int kk=0;kk<64;kk++){
            float hk = __shfl(hold,kk);
            hr += hk*lwr[kk];
            hz += hk*lwz[kk];
            hn += hk*lwn[kk];
        }
        const float* g = GI + ((size_t)t*NN+node)*192;
        float r  = sigm(g[j]     + hr);
        float z  = sigm(g[64+j]  + hz);
        float nn_= tanhf(g[128+j] + r*hn);
        hold = (1.f-z)*nn_ + z*hold;
        Hall[((size_t)t*NN+node)*64 + j] = hold;
    }
}

// ---------------- K2: per-(t,n) P,Q + xh + a_s,a_d (R2 proven form) ----------------
__global__ void __launch_bounds__(256) k_post(const float* __restrict__ Hall,
                       const float* __restrict__ Ws1, const float* __restrict__ Wgat,
                       const float* __restrict__ atts, const float* __restrict__ attd,
                       float* __restrict__ P, float* __restrict__ Q,
                       float* __restrict__ xh, float* __restrict__ as_, float* __restrict__ ad_){
    __shared__ float ws1l[128*64];
    __shared__ float wgl[64*32];
    int tid = threadIdx.x;
    for(int i=tid;i<128*64;i+=256) ws1l[i]=Ws1[i];
    for(int i=tid;i<64*32;i+=256)  wgl[i]=Wgat[i];
    __syncthreads();
    int bn = blockIdx.x*4 + (tid>>6);
    int j = tid&63;
    float hv = Hall[(size_t)bn*64+j];
    float p=0.f,q=0.f,xv=0.f;
    for(int kk=0;kk<64;kk++){
        float hk=__shfl(hv,kk);
        p += hk*ws1l[kk*64+j];
        q += hk*ws1l[(64+kk)*64+j];
        if(j<32) xv += hk*wgl[kk*32+j];
    }
    P[(size_t)bn*64+j]=p; Q[(size_t)bn*64+j]=q;
    if(j<32){
        xh[(size_t)bn*32+j]=xv;
        float asv = xv*atts[j];
        float adv = xv*attd[j];
        for(int m=1;m<8;m<<=1){ asv += __shfl_xor(asv,m); adv += __shfl_xor(adv,m); }
        if((j&7)==0){ as_[(size_t)bn*4+(j>>3)]=asv; ad_[(size_t)bn*4+(j>>3)]=adv; }
    }
}

// ---------------- K3: edge scores + per-source-row top-k, all t ----------------
// Per-lane edge: lane owns one edge, 16 independent float4 loads; Q is L2-resident.
__global__ void __launch_bounds__(256) k_edge(const float* __restrict__ P, const float* __restrict__ Q,
                       const float* __restrict__ bs1, const float* __restrict__ Ws2,
                       const float* __restrict__ bs2, const int* __restrict__ dst,
                       const int* __restrict__ kptr, float* __restrict__ wbuf){
    int tid = threadIdx.x;
    int t = blockIdx.y;
    int row = blockIdx.x*8 + (tid>>5);
    int d = tid & 31;
    int e = row*DG + d;
    int de = dst[e];
    const float4* Pr = (const float4*)(P + ((size_t)t*NN+row)*64);
    const float4* Qr = (const float4*)(Q + ((size_t)t*NN+de)*64);
    const float4* B1 = (const float4*)bs1;
    const float4* W2 = (const float4*)Ws2;
    float acc = 0.f;
    #pragma unroll
    for(int jj=0;jj<16;jj++){
        float4 pv=Pr[jj], qv=Qr[jj], bv=B1[jj], wv=W2[jj];
        acc += fmaxf(pv.x+qv.x+bv.x,0.f)*wv.x;
        acc += fmaxf(pv.y+qv.y+bv.y,0.f)*wv.y;
        acc += fmaxf(pv.z+qv.z+bv.z,0.f)*wv.z;
        acc += fmaxf(pv.w+qv.w+bv.w,0.f)*wv.w;
    }
    float score = sigm(acc + bs2[0]);
    int kk = kptr[0]; if(kk>32) kk=32; if(kk<0) kk=0;
    bool sel=false;
    for(int it=0; it<kk; it++){
        float v = sel ? -INFINITY : score;
        int idx = d;
        for(int m=16;m>=1;m>>=1){
            float ov = __shfl_xor(v,m,32);
            int   oi = __shfl_xor(idx,m,32);
            if(ov>v || (ov==v && oi<idx)){ v=ov; idx=oi; }  // lax.top_k tie-break: lowest index
        }
        if(idx==d) sel=true;
    }
    wbuf[(size_t)t*EE + e] = sel ? score : 0.f;
}

// ---------------- K4: per-dst masked softmax + message aggregation, all t ----------------
__global__ void __launch_bounds__(256) k_soft(const int* __restrict__ indptr, const int* __restrict__ eids,
                       const float* __restrict__ as_, const float* __restrict__ ad_,
                       const float* __restrict__ wbuf, const float* __restrict__ xhb,
                       const float* __restrict__ bgat,
                       float* __restrict__ alphab, float* __restrict__ outp){
    int n = blockIdx.x;
    int t = blockIdx.y;
    int h = threadIdx.x>>6;
    int lane = threadIdx.x&63;
    const float* w     = wbuf  + (size_t)t*EE;
    const float* asb   = as_   + (size_t)t*NN*4;
    const float* xhbt  = xhb   + (size_t)t*NN*32;
    float*       alpha = alphab+ (size_t)t*EE*4;
    int beg = indptr[n], end = indptr[n+1];
    int deg = end-beg;
    float adv = ad_[((size_t)t*NN+n)*4+h];
    float acc[8];
    #pragma unroll
    for(int c=0;c<8;c++) acc[c]=0.f;
    if(deg<=64){
        bool valid = lane<deg;
        int e = valid ? eids[beg+lane] : 0;
        float we = valid ? w[e] : 0.f;
        bool kept = we>0.f;
        int s = e>>5;
        float lg = -INFINITY, ex = 0.f;
        if(kept){
            lg = asb[s*4+h]+adv;
            lg = lg>0.f ? lg : 0.2f*lg;
        }
        float m = lg;
        for(int mm=32;mm>=1;mm>>=1) m = fmaxf(m,__shfl_xor(m,mm));
        if(kept) ex = expf(lg-m);
        float ssum = ex;
        for(int mm=32;mm>=1;mm>>=1) ssum += __shfl_xor(ssum,mm);
        float inv = 1.0f/fmaxf(ssum,1e-16f);
        if(kept){
            float a = ex*inv;
            alpha[e*4+h] = a;
            float aw = a*we;
            const float4* xr = (const float4*)(xhbt + s*32 + h*8);
            float4 x0 = xr[0], x1 = xr[1];
            acc[0]+=aw*x0.x; acc[1]+=aw*x0.y; acc[2]+=aw*x0.z; acc[3]+=aw*x0.w;
            acc[4]+=aw*x1.x; acc[5]+=aw*x1.y; acc[6]+=aw*x1.z; acc[7]+=aw*x1.w;
        }
    } else {
        float m = -INFINITY;
        for(int i=beg+lane;i<end;i+=64){
            int e = eids[i];
            if(w[e]>0.f){
                float lg = asb[(e>>5)*4+h]+adv;
                lg = lg>0.f ? lg : 0.2f*lg;
                m = fmaxf(m,lg);
            }
        }
        for(int mm=32;mm>=1;mm>>=1) m = fmaxf(m,__shfl_xor(m,mm));
        float ssum=0.f;
        for(int i=beg+lane;i<end;i+=64){
            int e = eids[i];
            float ex = 0.f;
            if(w[e]>0.f){
                float lg = asb[(e>>5)*4+h]+adv;
                lg = lg>0.f ? lg : 0.2f*lg;
                ex = expf(lg-m);
            }
            alpha[e*4+h]=ex;
            ssum += ex;
        }
        for(int mm=32;mm>=1;mm>>=1) ssum += __shfl_xor(ssum,mm);
        float inv = 1.0f/fmaxf(ssum,1e-16f);
        for(int i=beg+lane;i<end;i+=64){
            int e = eids[i];
            if(w[e]>0.f){
                float a = alpha[e*4+h]*inv;
                alpha[e*4+h]=a;
                float aw = a*w[e];
                const float* xr = xhbt + (e>>5)*32 + h*8;
                #pragma unroll
                for(int c=0;c<8;c++) acc[c] += aw*xr[c];
            }
        }
    }
    for(int mm=32;mm>=1;mm>>=1){
        #pragma unroll
        for(int c=0;c<8;c++) acc[c] += __shfl_xor(acc[c],mm);
    }
    if(lane==0){
        float* o = outp + ((size_t)t*NN+n)*32 + h*8;
        float4 o0 = { acc[0]+bgat[h*8+0], acc[1]+bgat[h*8+1], acc[2]+bgat[h*8+2], acc[3]+bgat[h*8+3] };
        float4 o1 = { acc[4]+bgat[h*8+4], acc[5]+bgat[h*8+5], acc[6]+bgat[h*8+6], acc[7]+bgat[h*8+7] };
        ((float4*)o)[0]=o0; ((float4*)o)[1]=o1;
    }
}

// ---------------- K5: sparse-aware dense A row write, all t ----------------
// <=k nonzeros per row compacted into LDS; stream float4 zeros with patched entries.
__global__ void __launch_bounds__(256) k_scatter(const float* __restrict__ alphab,
                       const float* __restrict__ wbuf,
                       const int* __restrict__ dst, float* __restrict__ attn){
    __shared__ int   kde[DG];
    __shared__ float kan[DG][NHEAD];
    __shared__ int   scnt;
    int n = blockIdx.x;
    int t = blockIdx.y;
    int tid = threadIdx.x;
    const float* alpha = alphab + (size_t)t*EE*4;
    const float* w     = wbuf   + (size_t)t*EE;
    if(tid<64){
        int d = tid;
        int e = n*DG + d;
        bool kept = false;
        if(d<DG) kept = (w[e] > 0.f);
        unsigned long long mask = __ballot(kept);
        float4 av = {0.f,0.f,0.f,0.f};
        int de = 0;
        if(kept){ de = dst[e]; av = *(const float4*)(alpha + (size_t)e*4); }
        float s0=av.x, s1=av.y, s2=av.z, s3=av.w;
        for(int m=32;m>=1;m>>=1){
            s0 += __shfl_xor(s0,m); s1 += __shfl_xor(s1,m);
            s2 += __shfl_xor(s2,m); s3 += __shfl_xor(s3,m);
        }
        if(kept){
            int pos = __popcll(mask & ((1ull<<d)-1ull));
            kde[pos] = de;
            kan[pos][0] = av.x / fmaxf(s0,1e-9f);
            kan[pos][1] = av.y / fmaxf(s1,1e-9f);
            kan[pos][2] = av.z / fmaxf(s2,1e-9f);
            kan[pos][3] = av.w / fmaxf(s3,1e-9f);
        }
        if(tid==0) scnt = __popcll(mask);
    }
    __syncthreads();
    int cnt = scnt;
    size_t base = (size_t)t*NHEAD*NN*NN + (size_t)n*NN;
    #pragma unroll
    for(int it=0; it<6; it++){
        int c = it*256 + tid;          // 0..1535 over (head, 16B-chunk)
        int h = c/(NN/4), c4 = c%(NN/4);
        float4 f4 = {0.f,0.f,0.f,0.f};
        for(int p=0;p<cnt;p++){
            int de = kde[p];
            if((de>>2)==c4) ((float*)&f4)[de&3] += kan[p][h];
        }
        ((float4*)(attn + base + (size_t)h*NN*NN))[c4] = f4;
    }
}

extern "C" void kernel_launch(void* const* d_in, const int* in_sizes, int n_in,
                              void* d_out, int out_size, void* d_ws, size_t ws_size,
                              hipStream_t stream) {
    const float* Ht   = (const float*)d_in[0];
    const int*   dst  = (const int*)  d_in[2];
    const int*   kptr = (const int*)  d_in[3];
    const float* We1  = (const float*)d_in[4];
    const float* be1  = (const float*)d_in[5];
    const float* We2  = (const float*)d_in[6];
    const float* be2  = (const float*)d_in[7];
    const float* lng  = (const float*)d_in[8];
    const float* lnb  = (const float*)d_in[9];
    const float* Wih  = (const float*)d_in[10];
    const float* Whh  = (const float*)d_in[11];
    const float* bih  = (const float*)d_in[12];
    const float* bhh  = (const float*)d_in[13];
    const float* Ws1  = (const float*)d_in[14];
    const float* bs1  = (const float*)d_in[15];
    const float* Ws2  = (const float*)d_in[16];
    const float* bs2  = (const float*)d_in[17];
    const float* Wgat = (const float*)d_in[18];
    const float* atts = (const float*)d_in[19];
    const float* attd = (const float*)d_in[20];
    const float* bgat = (const float*)d_in[21];

    float* outp = (float*)d_out;                       // (B,N,32)
    float* attn = outp + (size_t)BB*NN*32;             // (B,HEADS,N,N)

    float* ws    = (float*)d_ws;
    float* GI    = ws;                    // 2359296
    float* Hall  = ws + 2359296;          //  786432
    float* P     = ws + 3145728;          //  786432
    float* Q     = ws + 3932160;          //  786432
    float* xh    = ws + 4718592;          //  393216
    float* as_   = ws + 5111808;          //   49152
    float* ad_   = ws + 5160960;          //   49152
    float* wbuf  = ws + 5210112;          //  393216
    float* alpha = ws + 5603328;          // 1572864
    int*   ibase = (int*)(ws + 7176192);
    int*   cursor= ibase;                 // NN
    int*   indptr= ibase + 2048;          // NN+1
    int*   eids  = ibase + 4096;          // EE

    k_embgi<<<BB*NN/4, 256, 0, stream>>>(Ht, We1, be1, We2, be2, lng, lnb, Wih, bih, GI, cursor);
    k_count<<<EE/256, 256, 0, stream>>>(dst, cursor);
    k_scan<<<1, 256, 0, stream>>>(cursor, indptr);
    k_fill<<<EE/256, 256, 0, stream>>>(dst, cursor, eids);
    k_gru_all<<<NN/6, 384, 0, stream>>>(GI, Whh, bhh, Hall);
    k_post<<<BB*NN/4, 256, 0, stream>>>(Hall, Ws1, Wgat, atts, attd, P, Q, xh, as_, ad_);
    {
        dim3 ge(NN/8, BB);
        k_edge<<<ge, 256, 0, stream>>>(P, Q, bs1, Ws2, bs2, dst, kptr, wbuf);
        dim3 g(NN, BB);
        k_soft<<<g, 256, 0, stream>>>(indptr, eids, as_, ad_, wbuf, xh, bgat, alpha, outp);
        k_scatter<<<g, 256, 0, stream>>>(alpha, wbuf, dst, attn);
    }
}